// Round 6
// baseline (323.539 us; speedup 1.0000x reference)
//
#include <hip/hip_runtime.h>
#include <stdint.h>

typedef short short8 __attribute__((ext_vector_type(8)));
typedef float floatx16 __attribute__((ext_vector_type(16)));
typedef unsigned int uint32;

#define NPTS (4 * 65536)
#define RGB_OFF (NPTS * 3)

// ---------- helpers ----------
__device__ __forceinline__ uint16_t bf_rne(float f) {
  uint32 u = __float_as_uint(f);
  u += 0x7FFFu + ((u >> 16) & 1u);
  return (uint16_t)(u >> 16);
}
// pack two f32 -> two bf16 (round-half-up) via v_perm_b32
__device__ __forceinline__ uint32 pack2(float a, float b) {
  return __builtin_amdgcn_perm(__float_as_uint(b) + 0x8000u,
                               __float_as_uint(a) + 0x8000u, 0x07060302u);
}
__device__ __forceinline__ float bf_lo(uint32 u) { return __uint_as_float(u << 16); }
__device__ __forceinline__ float bf_hi(uint32 u) { return __uint_as_float(u & 0xFFFF0000u); }
// exchange: a's upper 32 lanes <-> b's lower 32 lanes
__device__ __forceinline__ void swap32(uint32& a, uint32& b) {
  asm("v_permlane32_swap_b32 %0, %1" : "+v"(a), "+v"(b));
}
__device__ __forceinline__ void gacc(const uint16_t* p, float w, float* acc) {
  uint4 q = *(const uint4*)p;
  acc[0] += w * bf_lo(q.x);
  acc[1] += w * bf_hi(q.x);
  acc[2] += w * bf_lo(q.y);
  acc[3] += w * bf_hi(q.y);
  acc[4] += w * bf_lo(q.z);
  acc[5] += w * bf_hi(q.z);
  acc[6] += w * bf_lo(q.w);
  acc[7] += w * bf_hi(q.w);
}

// ---------- kernel 1: triplane (12,32,256,256) f32 -> (12,256,256,32) bf16 ----------
// 4 pixels/thread: all global loads are dwordx4 (1KB/wave/instr), stores 256B/lane.
__global__ __launch_bounds__(256) void k_tr(const float* __restrict__ tri,
                                            uint16_t* __restrict__ out) {
  const size_t pix = ((size_t)blockIdx.x * 256 + threadIdx.x) * 4;
  const int n = (int)(pix >> 16);
  const int rem = (int)(pix & 65535);
  const float* src = tri + ((size_t)n << 21) + rem;
  uint32 q[4][16];
#pragma unroll
  for (int c = 0; c < 16; ++c) {
    float4 a = *(const float4*)(src + ((size_t)(2 * c) << 16));
    float4 b = *(const float4*)(src + ((size_t)(2 * c + 1) << 16));
    q[0][c] = pack2(a.x, b.x);
    q[1][c] = pack2(a.y, b.y);
    q[2][c] = pack2(a.z, b.z);
    q[3][c] = pack2(a.w, b.w);
  }
  uint4* dst = (uint4*)(out + pix * 32);
#pragma unroll
  for (int j = 0; j < 4; ++j)
#pragma unroll
    for (int g = 0; g < 4; ++g)
      dst[j * 4 + g] =
          make_uint4(q[j][4 * g], q[j][4 * g + 1], q[j][4 * g + 2], q[j][4 * g + 3]);
}

// ---------- kernel 2: pack weights into MFMA A-frag layout + biases into C-layout ----------
// frag bases per layer: {0,20,52,84,104,136,168}, Ks={5,8,8,5,8,8,8}, 176 frags.
// frag(lay,mt,k): lane L holds W[mt*32+(L&31)][k*16+(L>>5)*8 + j], j=0..7 -> 16B
// packed-h column order: [feats 0..31 | freq 32..67 | pad 68..79].
__global__ __launch_bounds__(256) void k_pack(
    const float* __restrict__ w_in, const float* __restrict__ w_skip,
    const float* __restrict__ w_before, const float* __restrict__ w_after,
    const float* __restrict__ w_out, const float* __restrict__ b_in,
    const float* __restrict__ b_skip, const float* __restrict__ b_before,
    const float* __restrict__ b_after, const float* __restrict__ b_out,
    uint16_t* __restrict__ wpack, float* __restrict__ bpack) {
  const int blk = blockIdx.x;
  if (blk >= 44) {  // bias pack: bpack[l*128 + mt*32 + half*16 + reg]
    for (int t = threadIdx.x; t < 800; t += 256) {
      int l, idx;
      if (t < 768) { l = t >> 7; idx = t & 127; }
      else { l = 6; idx = t - 768; }
      int mt = idx >> 5, rem = idx & 31;
      int half = rem >> 4, r = rem & 15;
      int f = mt * 32 + (r & 3) + 8 * (r >> 2) + 4 * half;
      float v;
      switch (l) {
        case 0: v = b_in[f]; break;
        case 1: v = b_before[f]; break;
        case 2: v = b_before[128 + f]; break;
        case 3: v = b_skip[f]; break;
        case 4: v = b_after[f]; break;
        case 5: v = b_after[128 + f]; break;
        default: v = (f < 4) ? b_out[f] : 0.0f; break;
      }
      bpack[l * 128 + idx] = v;
    }
    return;
  }
  const int w = blk * 4 + (threadIdx.x >> 6);  // 0..175
  const int L = threadIdx.x & 63;
  int lay, mt, k;
  if (w < 20)      { lay = 0; mt = w / 5;        k = w - mt * 5; }
  else if (w < 52) { int u = w - 20;  lay = 1; mt = u >> 3; k = u & 7; }
  else if (w < 84) { int u = w - 52;  lay = 2; mt = u >> 3; k = u & 7; }
  else if (w < 104){ int u = w - 84;  lay = 3; mt = u / 5;  k = u - mt * 5; }
  else if (w < 136){ int u = w - 104; lay = 4; mt = u >> 3; k = u & 7; }
  else if (w < 168){ int u = w - 136; lay = 5; mt = u >> 3; k = u & 7; }
  else             { lay = 6; mt = 0; k = w - 168; }
  const float* W;
  int insk = 0;
  switch (lay) {
    case 0: W = w_in; insk = 1; break;
    case 1: W = w_before; break;
    case 2: W = w_before + 16384; break;
    case 3: W = w_skip; insk = 1; break;
    case 4: W = w_after; break;
    case 5: W = w_after + 16384; break;
    default: W = w_out; break;
  }
  const int frow = mt * 32 + (L & 31);
  const int kbase = k * 16 + (L >> 5) * 8;
  uint16_t h[8];
#pragma unroll
  for (int j = 0; j < 8; ++j) {
    int kl = kbase + j;
    float v;
    if (insk) {
      int col = (kl < 32) ? (36 + kl) : ((kl < 68) ? (kl - 32) : -1);
      v = (col < 0) ? 0.0f : W[frow * 68 + col];
    } else if (lay == 6) {
      v = (frow < 4) ? W[frow * 128 + kl] : 0.0f;
    } else {
      v = W[frow * 128 + kl];
    }
    h[j] = bf_rne(v);
  }
  uint4 q;
  q.x = (uint32)h[0] | ((uint32)h[1] << 16);
  q.y = (uint32)h[2] | ((uint32)h[3] << 16);
  q.z = (uint32)h[4] | ((uint32)h[5] << 16);
  q.w = (uint32)h[6] | ((uint32)h[7] << 16);
  *(uint4*)(wpack + (size_t)w * 512 + L * 8) = q;
}

// ---------- register-resident MLP machinery ----------
// C-layout per 32-row tile: r = (reg&3) + 8*(reg>>2) + 4*(lane>>5).
// B-layout: lane-half t holds k = t*8+j. Frag f (rows 16f..16f+15, s=f&1):
// B regs = {q0a,q0b,q1a,q1b} after swap32(q0a,q1a), swap32(q0b,q1b).

__device__ __forceinline__ void bias_init(floatx16* a, const float* __restrict__ bpack,
                                          int LAY, int kh) {
#pragma unroll
  for (int mt = 0; mt < 4; ++mt) {
    const float4* bp = (const float4*)(bpack + LAY * 128 + mt * 32 + kh * 16);
#pragma unroll
    for (int g = 0; g < 4; ++g) {
      float4 v = bp[g];
      a[mt][4 * g + 0] = v.x; a[mt][4 * g + 1] = v.y;
      a[mt][4 * g + 2] = v.z; a[mt][4 * g + 3] = v.w;
    }
  }
}

__device__ __forceinline__ void epi_dense(floatx16* a, short8* bout) {
#pragma unroll
  for (int f = 0; f < 8; ++f) {
    const int mt = f >> 1, s = f & 1;
    uint32 q0a = pack2(fmaxf(a[mt][8 * s + 0], 0.f), fmaxf(a[mt][8 * s + 1], 0.f));
    uint32 q0b = pack2(fmaxf(a[mt][8 * s + 2], 0.f), fmaxf(a[mt][8 * s + 3], 0.f));
    uint32 q1a = pack2(fmaxf(a[mt][8 * s + 4], 0.f), fmaxf(a[mt][8 * s + 5], 0.f));
    uint32 q1b = pack2(fmaxf(a[mt][8 * s + 6], 0.f), fmaxf(a[mt][8 * s + 7], 0.f));
    swap32(q0a, q1a);
    swap32(q0b, q1b);
    bout[f] = __builtin_bit_cast(short8, make_uint4(q0a, q0b, q1a, q1b));
  }
}

__device__ __forceinline__ void epi_skip(floatx16* a, short8* bio) {
#pragma unroll
  for (int f = 0; f < 8; ++f) {
    const int mt = f >> 1, s = f & 1;
    uint4 old = __builtin_bit_cast(uint4, bio[f]);
    uint32 uA = old.x, uB = old.y, uC = old.z, uD = old.w;
    swap32(uA, uC);  // involution: back to C-layout packed x2
    swap32(uB, uD);
    float r0 = fmaxf(a[mt][8 * s + 0], 0.f) + bf_lo(uA);
    float r1 = fmaxf(a[mt][8 * s + 1], 0.f) + bf_hi(uA);
    float r2 = fmaxf(a[mt][8 * s + 2], 0.f) + bf_lo(uB);
    float r3 = fmaxf(a[mt][8 * s + 3], 0.f) + bf_hi(uB);
    float r4 = fmaxf(a[mt][8 * s + 4], 0.f) + bf_lo(uC);
    float r5 = fmaxf(a[mt][8 * s + 5], 0.f) + bf_hi(uC);
    float r6 = fmaxf(a[mt][8 * s + 6], 0.f) + bf_lo(uD);
    float r7 = fmaxf(a[mt][8 * s + 7], 0.f) + bf_hi(uD);
    uint32 q0a = pack2(r0, r1), q0b = pack2(r2, r3);
    uint32 q1a = pack2(r4, r5), q1b = pack2(r6, r7);
    swap32(q0a, q1a);
    swap32(q0b, q1b);
    bio[f] = __builtin_bit_cast(short8, make_uint4(q0a, q0b, q1a, q1b));
  }
}

// dense layer, B input from registers
template <int LAY, int Ks, int FOFF>
__device__ __forceinline__ void layer_dense(const short8* bin, short8* bout,
                                            const uint16_t* __restrict__ wpack,
                                            const float* __restrict__ bpack, int L,
                                            int kh) {
  floatx16 a[4];
  bias_init(a, bpack, LAY, kh);
  const uint16_t* wp = wpack + (size_t)FOFF * 512 + L * 8;
#pragma unroll
  for (int k = 0; k < Ks; ++k) {
    short8 w0 = *(const short8*)(wp + (size_t)(0 * Ks + k) * 512);
    short8 w1 = *(const short8*)(wp + (size_t)(1 * Ks + k) * 512);
    short8 w2 = *(const short8*)(wp + (size_t)(2 * Ks + k) * 512);
    short8 w3 = *(const short8*)(wp + (size_t)(3 * Ks + k) * 512);
    a[0] = __builtin_amdgcn_mfma_f32_32x32x16_bf16(w0, bin[k], a[0], 0, 0, 0);
    a[1] = __builtin_amdgcn_mfma_f32_32x32x16_bf16(w1, bin[k], a[1], 0, 0, 0);
    a[2] = __builtin_amdgcn_mfma_f32_32x32x16_bf16(w2, bin[k], a[2], 0, 0, 0);
    a[3] = __builtin_amdgcn_mfma_f32_32x32x16_bf16(w3, bin[k], a[3], 0, 0, 0);
  }
  epi_dense(a, bout);
}

// h-input layer: B frags read per-k from wave-private LDS (no barrier needed)
template <int LAY, int Ks, int FOFF, bool SKIP>
__device__ __forceinline__ void layer_h(const uint16_t* __restrict__ hl, short8* bio,
                                        const uint16_t* __restrict__ wpack,
                                        const float* __restrict__ bpack, int L,
                                        int kh) {
  floatx16 a[4];
  bias_init(a, bpack, LAY, kh);
  const uint16_t* wp = wpack + (size_t)FOFF * 512 + L * 8;
#pragma unroll
  for (int k = 0; k < Ks; ++k) {
    short8 bk = *(const short8*)(hl + (size_t)k * 512);  // ds_read_b128
    short8 w0 = *(const short8*)(wp + (size_t)(0 * Ks + k) * 512);
    short8 w1 = *(const short8*)(wp + (size_t)(1 * Ks + k) * 512);
    short8 w2 = *(const short8*)(wp + (size_t)(2 * Ks + k) * 512);
    short8 w3 = *(const short8*)(wp + (size_t)(3 * Ks + k) * 512);
    a[0] = __builtin_amdgcn_mfma_f32_32x32x16_bf16(w0, bk, a[0], 0, 0, 0);
    a[1] = __builtin_amdgcn_mfma_f32_32x32x16_bf16(w1, bk, a[1], 0, 0, 0);
    a[2] = __builtin_amdgcn_mfma_f32_32x32x16_bf16(w2, bk, a[2], 0, 0, 0);
    a[3] = __builtin_amdgcn_mfma_f32_32x32x16_bf16(w3, bk, a[3], 0, 0, 0);
  }
  if (SKIP) epi_skip(a, bio);
  else epi_dense(a, bio);
}

// ---------- kernel 3: fused gather + encode + MLP, zero barriers ----------
// Wave owns 32 points. Lane L: point p = L&31, k-half kh = L>>5.
// h (layers 0/3 input) lives in wave-private LDS to keep unified regs <= 128.
template <int FAST>
__global__ __launch_bounds__(256, 4) void k_main(
    const uint16_t* __restrict__ trit, const float* __restrict__ trif,
    const float* __restrict__ coords, const uint16_t* __restrict__ wpack,
    const float* __restrict__ bpack, float* __restrict__ dout) {
  __shared__ __align__(16) uint16_t hlds[4 * 5 * 64 * 8];  // 20 KB: 4 waves x 5 frags
  const int t = threadIdx.x;
  const int L = t & 63;
  const int kh = L >> 5;
  const int p = (t >> 6) * 32 + (L & 31);
  const int pg = blockIdx.x * 128 + p;
  uint16_t* hl = hlds + ((size_t)((t >> 6) * 5) * 64 + L) * 8;  // frag k at +k*512

  // ---- phase 1: gather + freq encode -> wave-private LDS h ----
  float cx = coords[pg * 3 + 0], cy = coords[pg * 3 + 1], cz = coords[pg * 3 + 2];
  float f1x = cx + 1.0f, f1y = cy + 1.0f, f1z = cz + 1.0f;
  float nx = f1x * 0.5f, ny = f1y * 0.5f, nz = f1z * 0.5f;
  float sx = f1x - 1.0f, sy = f1y - 1.0f, sz = f1z - 1.0f;
  bool sel = (nx > 0.f) & (nx < 1.f) & (ny > 0.f) & (ny < 1.f) & (nz > 0.f) & (nz < 1.f);
  const int b = pg >> 16;
  float acc[16];
#pragma unroll
  for (int j = 0; j < 16; ++j) acc[j] = 0.f;
#pragma unroll
  for (int pl = 0; pl < 3; ++pl) {
    float gx = (pl == 2) ? sy : sx;
    float gy = (pl == 0) ? sy : sz;
    float ix = ((gx + 1.0f) * 0.5f) * 255.0f;
    float iy = ((gy + 1.0f) * 0.5f) * 255.0f;
    float x0f = floorf(ix), y0f = floorf(iy);
    float wx = ix - x0f, wy = iy - y0f;
    float vx0 = (x0f >= 0.0f && x0f < 256.0f) ? 1.f : 0.f;
    float vx1 = (x0f >= -1.0f && x0f < 255.0f) ? 1.f : 0.f;
    float vy0 = (y0f >= 0.0f && y0f < 256.0f) ? 1.f : 0.f;
    float vy1 = (y0f >= -1.0f && y0f < 255.0f) ? 1.f : 0.f;
    int x0 = min(max((int)x0f, 0), 255), x1 = min(max((int)x0f + 1, 0), 255);
    int y0 = min(max((int)y0f, 0), 255), y1 = min(max((int)y0f + 1, 0), 255);
    float w00 = (1.f - wx) * (1.f - wy) * vx0 * vy0;
    float w10 = wx * (1.f - wy) * vx1 * vy0;
    float w01 = (1.f - wx) * wy * vx0 * vy1;
    float w11 = wx * wy * vx1 * vy1;
    const int n = 3 * b + pl;
    if (FAST) {
      // lane's channel chunks: [kh*8, kh*8+8) and [16+kh*8, ...)
      const uint16_t* cb = trit + ((size_t)n << 21) + kh * 8;
      size_t o00 = (size_t)(y0 * 256 + x0) << 5, o10 = (size_t)(y0 * 256 + x1) << 5;
      size_t o01 = (size_t)(y1 * 256 + x0) << 5, o11 = (size_t)(y1 * 256 + x1) << 5;
      gacc(cb + o00, w00, acc); gacc(cb + 16 + o00, w00, acc + 8);
      gacc(cb + o10, w10, acc); gacc(cb + 16 + o10, w10, acc + 8);
      gacc(cb + o01, w01, acc); gacc(cb + 16 + o01, w01, acc + 8);
      gacc(cb + o11, w11, acc); gacc(cb + 16 + o11, w11, acc + 8);
    } else {
      const float* basef = trif + (((size_t)n * 32) << 16);
#pragma unroll
      for (int j = 0; j < 8; ++j) {
        const float* c0p = basef + (((size_t)(kh * 8 + j)) << 16);
        const float* c1p = basef + (((size_t)(16 + kh * 8 + j)) << 16);
        acc[j] += w00 * c0p[y0 * 256 + x0] + w10 * c0p[y0 * 256 + x1] +
                  w01 * c0p[y1 * 256 + x0] + w11 * c0p[y1 * 256 + x1];
        acc[8 + j] += w00 * c1p[y0 * 256 + x0] + w10 * c1p[y0 * 256 + x1] +
                      w01 * c1p[y1 * 256 + x0] + w11 * c1p[y1 * 256 + x1];
      }
    }
  }
  *(uint4*)(hl + 0 * 512) = make_uint4(pack2(acc[0], acc[1]), pack2(acc[2], acc[3]),
                                       pack2(acc[4], acc[5]), pack2(acc[6], acc[7]));
  *(uint4*)(hl + 1 * 512) =
      make_uint4(pack2(acc[8], acc[9]), pack2(acc[10], acc[11]),
                 pack2(acc[12], acc[13]), pack2(acc[14], acc[15]));
  {
    // freq cols 32+e, e = d*12 + (sin: k | cos: 6+k)
    float sv[3][6], cv[3][6];
#pragma unroll
    for (int d = 0; d < 3; ++d) {
      float nd = (d == 0) ? nx : (d == 1) ? ny : nz;
#pragma unroll
      for (int k = 0; k < 6; ++k) {
        float rev = nd * (0.5f * (float)(1 << k));
        float r = rev - rintf(rev);
        sv[d][k] = __builtin_amdgcn_sinf(r);
        cv[d][k] = __builtin_amdgcn_cosf(r);
      }
    }
    if (kh == 0) {
      *(uint4*)(hl + 2 * 512) =  // e 0..7: d0 s0-5, d0 c0-1
          make_uint4(pack2(sv[0][0], sv[0][1]), pack2(sv[0][2], sv[0][3]),
                     pack2(sv[0][4], sv[0][5]), pack2(cv[0][0], cv[0][1]));
      *(uint4*)(hl + 3 * 512) =  // e 16..23: d1 s4-5, d1 c0-5
          make_uint4(pack2(sv[1][4], sv[1][5]), pack2(cv[1][0], cv[1][1]),
                     pack2(cv[1][2], cv[1][3]), pack2(cv[1][4], cv[1][5]));
      *(uint4*)(hl + 4 * 512) =  // e 32..35: d2 c2-5, then pad
          make_uint4(pack2(cv[2][2], cv[2][3]), pack2(cv[2][4], cv[2][5]), 0u, 0u);
    } else {
      *(uint4*)(hl + 2 * 512) =  // e 8..15: d0 c2-5, d1 s0-3
          make_uint4(pack2(cv[0][2], cv[0][3]), pack2(cv[0][4], cv[0][5]),
                     pack2(sv[1][0], sv[1][1]), pack2(sv[1][2], sv[1][3]));
      *(uint4*)(hl + 3 * 512) =  // e 24..31: d2 s0-5, d2 c0-1
          make_uint4(pack2(sv[2][0], sv[2][1]), pack2(sv[2][2], sv[2][3]),
                     pack2(sv[2][4], sv[2][5]), pack2(cv[2][0], cv[2][1]));
      *(uint4*)(hl + 4 * 512) = make_uint4(0u, 0u, 0u, 0u);
    }
  }

  // ---- phase 2: MLP, activations register-resident, weights streamed from L2 ----
  short8 bf[8];
  layer_h<0, 5, 0, false>(hl, bf, wpack, bpack, L, kh);
  layer_dense<1, 8, 20>(bf, bf, wpack, bpack, L, kh);
  layer_dense<2, 8, 52>(bf, bf, wpack, bpack, L, kh);
  layer_h<3, 5, 84, true>(hl, bf, wpack, bpack, L, kh);
  layer_dense<4, 8, 104>(bf, bf, wpack, bpack, L, kh);
  layer_dense<5, 8, 136>(bf, bf, wpack, bpack, L, kh);

  // ---- output layer: w_out padded to 32x128, only rows 0..3 real ----
  {
    floatx16 a;
    const float4* bp = (const float4*)(bpack + 768 + kh * 16);
#pragma unroll
    for (int g = 0; g < 4; ++g) {
      float4 v = bp[g];
      a[4 * g + 0] = v.x; a[4 * g + 1] = v.y; a[4 * g + 2] = v.z; a[4 * g + 3] = v.w;
    }
    const uint16_t* wp = wpack + (size_t)168 * 512 + L * 8;
#pragma unroll
    for (int k = 0; k < 8; ++k) {
      short8 af = *(const short8*)(wp + (size_t)k * 512);
      a = __builtin_amdgcn_mfma_f32_32x32x16_bf16(af, bf[k], a, 0, 0, 0);
    }
    if (kh == 0) {  // regs 0..3 = out features 0..3 for point pg
      const float l2e = 1.44269504f;
      float r0 = 1.0f / (1.0f + exp2f(-l2e * a[0]));
      float r1 = 1.0f / (1.0f + exp2f(-l2e * a[1]));
      float r2 = 1.0f / (1.0f + exp2f(-l2e * a[2]));
      float dens = exp2f((a[3] - 1.0f) * l2e) * (sel ? 1.0f : 0.0f);
      dout[pg * 3 + 0] = r0;
      dout[pg * 3 + 1] = r1;
      dout[pg * 3 + 2] = r2;
      dout[RGB_OFF + pg] = dens;
    }
  }
}

extern "C" void kernel_launch(void* const* d_in, const int* in_sizes, int n_in,
                              void* d_out, int out_size, void* d_ws, size_t ws_size,
                              hipStream_t stream) {
  const float* tri = (const float*)d_in[0];
  const float* coords = (const float*)d_in[1];
  const float* w_in = (const float*)d_in[2];
  const float* b_in = (const float*)d_in[3];
  const float* w_skip = (const float*)d_in[4];
  const float* b_skip = (const float*)d_in[5];
  const float* w_bef = (const float*)d_in[6];
  const float* b_bef = (const float*)d_in[7];
  const float* w_aft = (const float*)d_in[8];
  const float* b_aft = (const float*)d_in[9];
  const float* w_out = (const float*)d_in[10];
  const float* b_out = (const float*)d_in[11];
  const size_t TRI_B = (size_t)12 * 256 * 256 * 32 * 2;  // 50,331,648
  const size_t WP_B = (size_t)176 * 1024;                // 180,224
  const size_t BP_B = 3200;
  char* ws = (char*)d_ws;
  const int fast = (ws_size >= TRI_B + WP_B + BP_B) ? 1 : 0;
  uint16_t* trit;
  uint16_t* wpk;
  float* bpk;
  if (fast) {
    trit = (uint16_t*)ws;
    wpk = (uint16_t*)(ws + TRI_B);
    bpk = (float*)(ws + TRI_B + WP_B);
  } else {
    trit = (uint16_t*)ws;  // unused
    wpk = (uint16_t*)ws;
    bpk = (float*)(ws + WP_B);
  }
  if (fast) k_tr<<<dim3(768), dim3(256), 0, stream>>>(tri, trit);
  k_pack<<<dim3(45), dim3(256), 0, stream>>>(w_in, w_skip, w_bef, w_aft, w_out,
                                             b_in, b_skip, b_bef, b_aft, b_out,
                                             wpk, bpk);
  if (fast)
    k_main<1><<<dim3(2048), dim3(256), 0, stream>>>(trit, tri, coords, wpk, bpk,
                                                    (float*)d_out);
  else
    k_main<0><<<dim3(2048), dim3(256), 0, stream>>>(trit, tri, coords, wpk, bpk,
                                                    (float*)d_out);
}